// Round 7
// baseline (7031.960 us; speedup 1.0000x reference)
//
#include <hip/hip_runtime.h>
#include <hip/hip_fp16.h>
#include <cmath>

// Problem constants (reference: B=256, T=512, IN=64, R=2048)
constexpr int kB  = 256;
constexpr int kT  = 512;
constexpr int kIN = 64;
constexpr int kR  = 2048;

constexpr int kBlocks = 256;   // 4 m-bands x 64 n-blocks -> 1 block/CU, all resident
constexpr int BN = 32;         // n per block (W-band in registers)
constexpr int BM = 64;         // batches per block
constexpr int CH  = 256;       // k per chunk (= 8 producer blocks' slices)
constexpr int NCH = kR / CH;   // 8 chunks = 8 flag groups
constexpr int PFS = 36;        // partial-scratch row stride (words)
constexpr int kNB = 64;        // n-blocks per m-band

typedef _Float16 f16x8 __attribute__((ext_vector_type(8)));
typedef float    f32x4 __attribute__((ext_vector_type(4)));
typedef unsigned long long u64;

#define MFMA16(a, b, c) __builtin_amdgcn_mfma_f32_16x16x32_f16((a), (b), (c), 0, 0, 0)

__device__ __forceinline__ f16x8 cvt8(float4 a, float4 b) {
    f16x8 v;
    v[0] = (_Float16)a.x; v[1] = (_Float16)a.y; v[2] = (_Float16)a.z; v[3] = (_Float16)a.w;
    v[4] = (_Float16)b.x; v[5] = (_Float16)b.y; v[6] = (_Float16)b.z; v[7] = (_Float16)b.w;
    return v;
}

// One coalesced poll of the band's 64 per-block flags (sc1 load, always fresh).
__device__ __forceinline__ u64 poll_flags(const unsigned* f, int lane, unsigned target) {
    unsigned v = __hip_atomic_load(f + lane, __ATOMIC_RELAXED, __HIP_MEMORY_SCOPE_AGENT);
    return __ballot(v >= target);
}

// Persistent ESN, r7: wave-autonomous K-loop.
// No LDS staging for s: each wave (mh, q) loads its exact A-fragment partition
// straight from global (L2-served after the per-step inv), ring-ordered with a
// depth-2 register pipeline and per-wave flag polls. Only 2 __syncthreads per
// step remain (post-inv, epilogue reduce). Coherence protocol as r5/r6:
// agent-scope write-through stores -> drain -> flag; ONE acquire-inv per block
// per step. Compiler memory barrier after each flag-wait pins load issue after
// publication confirm (L2-fill invariant keeps lines fresh; max band skew < 2
// steps by the flag-chain argument, so ping-pong reuse is safe).
__global__ __launch_bounds__(512, 2) void esn_persist(
    const float* __restrict__ X,     // [B, T, IN]
    const float* __restrict__ Win,   // [R, IN]
    const float* __restrict__ W,     // [R, R]
    float* __restrict__ out,         // [B, R]
    _Float16* __restrict__ sbuf0,
    _Float16* __restrict__ sbuf1,
    unsigned* __restrict__ flags)    // [4][64], zeroed at launch
{
    __shared__ __align__(16) float pf[4 * 64 * PFS];   // 36864 B partial scratch

    const int tid  = threadIdx.x;
    const int wave = tid >> 6, lane = tid & 63;
    const int quad = lane >> 4, l16 = lane & 15;
    const int mh = wave >> 2;        // m-half: rows [mh*32, mh*32+32)
    const int q  = wave & 3;         // k-phase: kk ≡ q (mod 4)
    const int nb = blockIdx.x & 63;  // n-block within band
    const int mb = blockIdx.x >> 6;  // m-band
    const int n0 = nb * BN;
    const int m0 = mb * BM;
    const int c0 = nb >> 3;          // own flag group / ring start
    unsigned* bandflags = flags + mb * kNB;

    // ---- one-time: W-band -> register B-frags (f16), ring-permuted ----
    // Ring pos c -> physical chunk p(c) = (c0+c)&7.
    // wfrag[h][2c+half] = W[n0+h*16+l16][kk*32 + quad*8 + j], kk = p(c)*8+half*4+q
    f16x8 wfrag[2][2 * NCH];
    #pragma unroll
    for (int h = 0; h < 2; ++h) {
        const float* wrow = W + (size_t)(n0 + h * 16 + l16) * kR;
        #pragma unroll
        for (int kki = 0; kki < 2 * NCH; ++kki) {
            const int kk = (((c0 + (kki >> 1)) & 7) << 3) + (kki & 1) * 4 + q;
            const float* p = wrow + kk * 32 + quad * 8;
            wfrag[h][kki] = cvt8(*(const float4*)p, *(const float4*)(p + 4));
        }
    }
    f16x8 winfrag[2] = {};
    if (q < 2) {
        #pragma unroll
        for (int h = 0; h < 2; ++h) {
            const float* p = Win + (size_t)(n0 + h * 16 + l16) * kIN + q * 32 + quad * 8;
            winfrag[h] = cvt8(*(const float4*)p, *(const float4*)(p + 4));
        }
    }

    // A-frag global base offsets for this lane (i = m-tile 0/1):
    // s[m0 + (2mh+i)*16 + l16][ chunk*CH + half*128 + q*32 + quad*8 ]
    const size_t a0 = (size_t)(m0 + (2 * mh + 0) * 16 + l16) * kR + q * 32 + quad * 8;
    const size_t a1 = (size_t)(m0 + (2 * mh + 1) * 16 + l16) * kR + q * 32 + quad * 8;

    #pragma unroll 1
    for (int t = 0; t < kT; ++t) {
        // ---- X-frag raw loads for THIS step (latency hidden under sync) ----
        float4 xr[2][2];
        if (q < 2) {
            #pragma unroll
            for (int i = 0; i < 2; ++i) {
                const float* xp = X + ((size_t)(m0 + (2 * mh + i) * 16 + l16) * kT + t) * kIN
                                + q * 32 + quad * 8;
                xr[i][0] = *(const float4*)xp;
                xr[i][1] = *(const float4*)(xp + 4);
            }
        }

        f32x4 acc[2][2] = {};

        // ---- recurrent term over s_{t-1}: wave-autonomous ring ----
        if (t > 0) {
            const _Float16* sprev = (t & 1) ? sbuf0 : sbuf1;
            const unsigned target = (unsigned)t;   // flag >= t <=> s[t-1] published

            if (wave == 0) {
                if (lane == 0) {
                    // own group ready before the block-wide inv
                    u64 fm = poll_flags(bandflags, lane, target);  // lane0-only: scalar path
                    while (((__hip_atomic_load(bandflags + 8 * c0 + (0), __ATOMIC_RELAXED,
                                               __HIP_MEMORY_SCOPE_AGENT) >= target) ? 0 : 1))
                        __builtin_amdgcn_s_sleep(1);
                    (void)fm;
                }
                // full-wave re-check of own group, then ONE inv per block per step
                u64 fmask0 = poll_flags(bandflags, lane, target);
                while (((fmask0 >> (8 * c0)) & 0xffull) != 0xffull) {
                    __builtin_amdgcn_s_sleep(1);
                    fmask0 = poll_flags(bandflags, lane, target);
                }
                __builtin_amdgcn_fence(__ATOMIC_ACQUIRE, "agent");
            }
            __syncthreads();

            u64 fmask = poll_flags(bandflags, lane, target);
            asm volatile("" ::: "memory");

            f16x8 pre[2][2][2];  // [parity][i(m-tile)][half]
            // ring 0 (own group, confirmed) and ring 1
            {
                const size_t off0 = (size_t)c0 * CH;
                pre[0][0][0] = *(const f16x8*)(sprev + a0 + off0);
                pre[0][0][1] = *(const f16x8*)(sprev + a0 + off0 + 128);
                pre[0][1][0] = *(const f16x8*)(sprev + a1 + off0);
                pre[0][1][1] = *(const f16x8*)(sprev + a1 + off0 + 128);
                const int rg1 = (c0 + 1) & 7;
                while (((fmask >> (8 * rg1)) & 0xffull) != 0xffull) {
                    __builtin_amdgcn_s_sleep(1);
                    fmask = poll_flags(bandflags, lane, target);
                }
                asm volatile("" ::: "memory");
                const size_t off1 = (size_t)rg1 * CH;
                pre[1][0][0] = *(const f16x8*)(sprev + a0 + off1);
                pre[1][0][1] = *(const f16x8*)(sprev + a0 + off1 + 128);
                pre[1][1][0] = *(const f16x8*)(sprev + a1 + off1);
                pre[1][1][1] = *(const f16x8*)(sprev + a1 + off1 + 128);
            }

            #pragma unroll
            for (int c = 0; c < NCH; ++c) {
                // compute ring pos c from pre[c&1]
                #pragma unroll
                for (int half = 0; half < 2; ++half) {
                    acc[0][0] = MFMA16(pre[c & 1][0][half], wfrag[0][2 * c + half], acc[0][0]);
                    acc[0][1] = MFMA16(pre[c & 1][0][half], wfrag[1][2 * c + half], acc[0][1]);
                    acc[1][0] = MFMA16(pre[c & 1][1][half], wfrag[0][2 * c + half], acc[1][0]);
                    acc[1][1] = MFMA16(pre[c & 1][1][half], wfrag[1][2 * c + half], acc[1][1]);
                }
                if (c + 2 < NCH) {
                    const int rg = (c0 + c + 2) & 7;
                    if (((fmask >> (8 * rg)) & 0xffull) != 0xffull) {
                        do {
                            __builtin_amdgcn_s_sleep(1);
                            fmask = poll_flags(bandflags, lane, target);
                        } while (((fmask >> (8 * rg)) & 0xffull) != 0xffull);
                    }
                    asm volatile("" ::: "memory");
                    const size_t off = (size_t)rg * CH;
                    pre[c & 1][0][0] = *(const f16x8*)(sprev + a0 + off);
                    pre[c & 1][0][1] = *(const f16x8*)(sprev + a0 + off + 128);
                    pre[c & 1][1][0] = *(const f16x8*)(sprev + a1 + off);
                    pre[c & 1][1][1] = *(const f16x8*)(sprev + a1 + off + 128);
                }
            }
        }

        // ---- input term (X loads long done) ----
        if (q < 2) {
            #pragma unroll
            for (int i = 0; i < 2; ++i) {
                f16x8 a = cvt8(xr[i][0], xr[i][1]);
                acc[i][0] = MFMA16(a, winfrag[0], acc[i][0]);
                acc[i][1] = MFMA16(a, winfrag[1], acc[i][1]);
            }
        }

        // ---- reduce 4 k-phase partials through LDS, tanh, store ----
        #pragma unroll
        for (int i = 0; i < 2; ++i)
            #pragma unroll
            for (int h = 0; h < 2; ++h)
                #pragma unroll
                for (int r = 0; r < 4; ++r)
                    pf[q * 64 * PFS + (mh * 32 + i * 16 + quad * 4 + r) * PFS + h * 16 + l16]
                        = acc[i][h][r];
        __syncthreads();

        const int ml = tid >> 3, nl4 = (tid & 7) * 4;
        f32x4 v0 = *(const f32x4*)&pf[0 * 64 * PFS + ml * PFS + nl4];
        f32x4 v1 = *(const f32x4*)&pf[1 * 64 * PFS + ml * PFS + nl4];
        f32x4 v2 = *(const f32x4*)&pf[2 * 64 * PFS + ml * PFS + nl4];
        f32x4 v3 = *(const f32x4*)&pf[3 * 64 * PFS + ml * PFS + nl4];
        float o0 = tanhf(v0[0] + v1[0] + v2[0] + v3[0]);
        float o1 = tanhf(v0[1] + v1[1] + v2[1] + v3[1]);
        float o2 = tanhf(v0[2] + v1[2] + v2[2] + v3[2]);
        float o3 = tanhf(v0[3] + v1[3] + v2[3] + v3[3]);

        if (t < kT - 1) {
            _Float16* sout = (t & 1) ? sbuf1 : sbuf0;
            union { u64 u; _Float16 h[4]; } pk;
            pk.h[0] = (_Float16)o0; pk.h[1] = (_Float16)o1;
            pk.h[2] = (_Float16)o2; pk.h[3] = (_Float16)o3;
            // write-through to the coherence point — no wbl2 anywhere
            __hip_atomic_store((u64*)(sout + (size_t)(m0 + ml) * kR + n0 + nl4), pk.u,
                               __ATOMIC_RELAXED, __HIP_MEMORY_SCOPE_AGENT);
            __builtin_amdgcn_s_waitcnt(0);   // this thread's stores completed
            __syncthreads();                 // whole block's stores completed; guards pf
            if (tid == 0)
                __hip_atomic_store(&bandflags[nb], (unsigned)(t + 1),
                                   __ATOMIC_RELAXED, __HIP_MEMORY_SCOPE_AGENT);
        } else {
            float4 o; o.x = o0; o.y = o1; o.z = o2; o.w = o3;
            *(float4*)(out + (size_t)(m0 + ml) * kR + n0 + nl4) = o;
        }
    }
}

extern "C" void kernel_launch(void* const* d_in, const int* in_sizes, int n_in,
                              void* d_out, int out_size, void* d_ws, size_t ws_size,
                              hipStream_t stream)
{
    const float* X   = (const float*)d_in[0];  // [B, T, IN]
    const float* Win = (const float*)d_in[1];  // [R, IN]
    const float* W   = (const float*)d_in[2];  // [R, R]
    float* out = (float*)d_out;                // [B, R]

    char* ws = (char*)d_ws;
    _Float16* s0 = (_Float16*)ws;                                  // 1 MB
    _Float16* s1 = (_Float16*)(ws + (size_t)kB * kR * 2);          // 1 MB
    unsigned* flags = (unsigned*)(ws + 2 * (size_t)kB * kR * 2);   // [4][64]

    hipMemsetAsync(flags, 0, 4 * kNB * sizeof(unsigned), stream);
    esn_persist<<<kBlocks, 512, 0, stream>>>(X, Win, W, out, s0, s1, flags);
}

// Round 8
// 5376.051 us; speedup vs baseline: 1.3080x; 1.3080x over previous
//
#include <hip/hip_runtime.h>
#include <hip/hip_fp16.h>
#include <cmath>

// Problem constants (reference: B=256, T=512, IN=64, R=2048)
constexpr int kB  = 256;
constexpr int kT  = 512;
constexpr int kIN = 64;
constexpr int kR  = 2048;

constexpr int kBlocks = 128;   // 4 m-bands x 32 n-blocks (latency-bound: CUs to spare)
constexpr int BN = 64;         // n per block (W-band in registers, n-split across waves)
constexpr int BM = 64;         // batches per block
constexpr int CH  = 256;       // k per staged s-chunk (= 4 producer blocks' slices)
constexpr int NCH = kR / CH;   // 8 chunks = 8 flag groups (4 blocks each)
constexpr int SST = CH + 8;    // ss row stride (halfs) = 264 -> 2-way-free banks
constexpr int PFS = 68;        // partial-scratch row stride (words), 16B-aligned rows
constexpr int kNB = 32;        // n-blocks per m-band

typedef _Float16 f16x8 __attribute__((ext_vector_type(8)));
typedef float    f32x4 __attribute__((ext_vector_type(4)));
typedef unsigned long long u64;

#define MFMA16(a, b, c) __builtin_amdgcn_mfma_f32_16x16x32_f16((a), (b), (c), 0, 0, 0)

__device__ __forceinline__ f16x8 cvt8(float4 a, float4 b) {
    f16x8 v;
    v[0] = (_Float16)a.x; v[1] = (_Float16)a.y; v[2] = (_Float16)a.z; v[3] = (_Float16)a.w;
    v[4] = (_Float16)b.x; v[5] = (_Float16)b.y; v[6] = (_Float16)b.z; v[7] = (_Float16)b.w;
    return v;
}

// One coalesced poll of the band's 32 per-block flags; ballot bit j (j<32) set
// iff band-block j has published step >= target.
__device__ __forceinline__ u64 poll_flags(const unsigned* f, int lane, unsigned target) {
    unsigned v = __hip_atomic_load(f + (lane & 31), __ATOMIC_RELAXED, __HIP_MEMORY_SCOPE_AGENT);
    return __ballot(v >= target);
}
__device__ __forceinline__ bool grp_ready(u64 fmask, int rg) {
    return ((fmask >> (4 * rg)) & 0xfull) == 0xfull;
}

// Persistent ESN, r8 = r6 structure (coalesced LDS staging — r7 proved direct
// per-lane fragment gathers are worse) with BN=64:
//   - 128 blocks: halves the per-step L3 broadcast (64 -> 32 MB) since each
//     block reads its whole band-slice of s regardless of BN;
//   - 16 MFMA/wave/chunk (vs 8): better cover for the chunk prefetch;
//   - waves = (n-half nh) x (k-phase q); 4-way k-partials reduced via LDS.
// Sync/coherence: per-band ring flags (groups of 4 producers), agent-scope
// write-through s-stores -> drain -> flag; ONE acquire-inv per block per step.
__global__ __launch_bounds__(512, 2) void esn_persist(
    const float* __restrict__ X,     // [B, T, IN]
    const float* __restrict__ Win,   // [R, IN]
    const float* __restrict__ W,     // [R, R]
    float* __restrict__ out,         // [B, R]
    _Float16* __restrict__ sbuf0,
    _Float16* __restrict__ sbuf1,
    unsigned* __restrict__ flags)    // [4][32], zeroed at launch
{
    // ss: 2 x 64 x SST halfs = 67584 B ; pf: 4 x 64 x PFS floats = 69632 B
    // (time-disjoint: pf only live after last chunk read, dead before staging)
    __shared__ __align__(16) char smem[69632];
    _Float16* ssb = (_Float16*)smem;
    float*    pf  = (float*)smem;

    const int tid  = threadIdx.x;
    const int wave = tid >> 6, lane = tid & 63;
    const int quad = lane >> 4, l16 = lane & 15;
    const int nh = wave >> 2;        // n-half: cols [nh*32, nh*32+32)
    const int q  = wave & 3;         // k-phase: kk ≡ q (mod 4)
    const int nb = blockIdx.x & 31;  // n-block within band
    const int mb = blockIdx.x >> 5;  // m-band
    const int n0 = nb * BN;
    const int m0 = mb * BM;
    const int c0 = nb >> 2;          // own flag group / ring start
    unsigned* bandflags = flags + mb * kNB;

    // ---- one-time: W-band -> register B-frags (f16), ring-permuted ----
    // Ring pos c -> physical chunk p(c) = (c0+c)&7.
    // wfrag[h][2c+half] = W[n0+nh*32+h*16+l16][kk*32+quad*8+j], kk=p(c)*8+half*4+q
    f16x8 wfrag[2][2 * NCH];
    #pragma unroll
    for (int h = 0; h < 2; ++h) {
        const float* wrow = W + (size_t)(n0 + nh * 32 + h * 16 + l16) * kR;
        #pragma unroll
        for (int kki = 0; kki < 2 * NCH; ++kki) {
            const int kk = (((c0 + (kki >> 1)) & 7) << 3) + (kki & 1) * 4 + q;
            const float* p = wrow + kk * 32 + quad * 8;
            wfrag[h][kki] = cvt8(*(const float4*)p, *(const float4*)(p + 4));
        }
    }
    f16x8 winfrag[2] = {};
    if (q < 2) {
        #pragma unroll
        for (int h = 0; h < 2; ++h) {
            const float* p = Win + (size_t)(n0 + nh * 32 + h * 16 + l16) * kIN
                           + q * 32 + quad * 8;
            winfrag[h] = cvt8(*(const float4*)p, *(const float4*)(p + 4));
        }
    }

    // s staging geometry: 4 rounds x 512 threads x 8 halfs (16 B), coalesced
    const int srow0 = tid >> 5;            // 0..15, +16 per round
    const int sc8   = (tid & 31) * 8;      // col within chunk (halfs)
    const size_t sgbase = (size_t)(m0 + srow0) * kR + sc8;

    #pragma unroll 1
    for (int t = 0; t < kT; ++t) {
        // ---- X-frag raw loads for THIS step (latency hidden under sync) ----
        float4 xr[4][2];
        if (q < 2) {
            #pragma unroll
            for (int i = 0; i < 4; ++i) {
                const float* xp = X + ((size_t)(m0 + i * 16 + l16) * kT + t) * kIN
                                + q * 32 + quad * 8;
                xr[i][0] = *(const float4*)xp;
                xr[i][1] = *(const float4*)(xp + 4);
            }
        }

        f32x4 acc[4][2] = {};   // [m-tile][n-tile within n-half]

        // ---- recurrent term over s_{t-1}, ring-ordered chunks ----
        if (t > 0) {
            const _Float16* sprev = (t & 1) ? sbuf0 : sbuf1;
            const unsigned target = (unsigned)t;   // flag >= t <=> s[t-1] published
            u64 fmask = 0;

            if (wave == 0) {
                fmask = poll_flags(bandflags, lane, target);
                while (!grp_ready(fmask, c0)) {
                    __builtin_amdgcn_s_sleep(1);
                    fmask = poll_flags(bandflags, lane, target);
                }
                // ONE inv per block per step: drop stale s lines from L1/L2
                __builtin_amdgcn_fence(__ATOMIC_ACQUIRE, "agent");
            }
            __syncthreads();
            if (wave != 0) fmask = poll_flags(bandflags, lane, target);

            // preload ring-0 (own group: k-offset c0*CH)
            #pragma unroll
            for (int r = 0; r < 4; ++r) {
                f16x8 v = *(const f16x8*)(sprev + sgbase + (size_t)(16 * r) * kR + c0 * CH);
                *(f16x8*)&ssb[(srow0 + 16 * r) * SST + sc8] = v;
            }
            __syncthreads();

            #pragma unroll
            for (int c = 0; c < NCH; ++c) {
                f16x8 pre[4];
                if (c + 1 < NCH) {
                    const int rg = (c0 + c + 1) & 7;       // physical chunk, ring pos c+1
                    while (!grp_ready(fmask, rg)) {
                        __builtin_amdgcn_s_sleep(1);
                        fmask = poll_flags(bandflags, lane, target);
                    }
                    #pragma unroll
                    for (int r = 0; r < 4; ++r)
                        pre[r] = *(const f16x8*)(sprev + sgbase + (size_t)(16 * r) * kR
                                                 + rg * CH);
                }
                const _Float16* buf = ssb + (c & 1) * 64 * SST;
                #pragma unroll
                for (int half = 0; half < 2; ++half) {
                    const int kloc = q * 32 + half * 128 + quad * 8;
                    #pragma unroll
                    for (int i = 0; i < 4; ++i) {
                        f16x8 av = *(const f16x8*)&buf[(i * 16 + l16) * SST + kloc];
                        acc[i][0] = MFMA16(av, wfrag[0][2 * c + half], acc[i][0]);
                        acc[i][1] = MFMA16(av, wfrag[1][2 * c + half], acc[i][1]);
                    }
                }
                if (c + 1 < NCH) {
                    _Float16* nbuf = ssb + ((c + 1) & 1) * 64 * SST;
                    #pragma unroll
                    for (int r = 0; r < 4; ++r)
                        *(f16x8*)&nbuf[(srow0 + 16 * r) * SST + sc8] = pre[r];
                }
                __syncthreads();
            }
        }

        // ---- input term (X loads long done) ----
        if (q < 2) {
            #pragma unroll
            for (int i = 0; i < 4; ++i) {
                f16x8 a = cvt8(xr[i][0], xr[i][1]);
                acc[i][0] = MFMA16(a, winfrag[0], acc[i][0]);
                acc[i][1] = MFMA16(a, winfrag[1], acc[i][1]);
            }
        }

        // ---- reduce 4 k-phase partials through LDS, tanh, store ----
        #pragma unroll
        for (int i = 0; i < 4; ++i)
            #pragma unroll
            for (int h = 0; h < 2; ++h)
                #pragma unroll
                for (int r = 0; r < 4; ++r)
                    pf[q * 64 * PFS + (i * 16 + quad * 4 + r) * PFS + nh * 32 + h * 16 + l16]
                        = acc[i][h][r];
        __syncthreads();

        // thread -> (m = tid>>3, 8 n at (tid&7)*8)
        const int ml = tid >> 3, nl8 = (tid & 7) * 8;
        float o[8];
        #pragma unroll
        for (int g = 0; g < 2; ++g) {
            f32x4 v0 = *(const f32x4*)&pf[0 * 64 * PFS + ml * PFS + nl8 + 4 * g];
            f32x4 v1 = *(const f32x4*)&pf[1 * 64 * PFS + ml * PFS + nl8 + 4 * g];
            f32x4 v2 = *(const f32x4*)&pf[2 * 64 * PFS + ml * PFS + nl8 + 4 * g];
            f32x4 v3 = *(const f32x4*)&pf[3 * 64 * PFS + ml * PFS + nl8 + 4 * g];
            #pragma unroll
            for (int e = 0; e < 4; ++e)
                o[4 * g + e] = tanhf(v0[e] + v1[e] + v2[e] + v3[e]);
        }

        if (t < kT - 1) {
            _Float16* sout = (t & 1) ? sbuf1 : sbuf0;
            union { u64 u[2]; _Float16 h[8]; } pk;
            #pragma unroll
            for (int e = 0; e < 8; ++e) pk.h[e] = (_Float16)o[e];
            u64* dst = (u64*)(sout + (size_t)(m0 + ml) * kR + n0 + nl8);
            // write-through to the coherence point — no wbl2 anywhere
            __hip_atomic_store(dst + 0, pk.u[0], __ATOMIC_RELAXED, __HIP_MEMORY_SCOPE_AGENT);
            __hip_atomic_store(dst + 1, pk.u[1], __ATOMIC_RELAXED, __HIP_MEMORY_SCOPE_AGENT);
            __builtin_amdgcn_s_waitcnt(0);   // this thread's stores completed
            __syncthreads();                 // whole block's stores completed; guards pf
            if (tid == 0)
                __hip_atomic_store(&bandflags[nb], (unsigned)(t + 1),
                                   __ATOMIC_RELAXED, __HIP_MEMORY_SCOPE_AGENT);
        } else {
            float* dst = out + (size_t)(m0 + ml) * kR + n0 + nl8;
            *(float4*)(dst + 0) = *(float4*)&o[0];
            *(float4*)(dst + 4) = *(float4*)&o[4];
        }
    }
}

extern "C" void kernel_launch(void* const* d_in, const int* in_sizes, int n_in,
                              void* d_out, int out_size, void* d_ws, size_t ws_size,
                              hipStream_t stream)
{
    const float* X   = (const float*)d_in[0];  // [B, T, IN]
    const float* Win = (const float*)d_in[1];  // [R, IN]
    const float* W   = (const float*)d_in[2];  // [R, R]
    float* out = (float*)d_out;                // [B, R]

    char* ws = (char*)d_ws;
    _Float16* s0 = (_Float16*)ws;                                  // 1 MB
    _Float16* s1 = (_Float16*)(ws + (size_t)kB * kR * 2);          // 1 MB
    unsigned* flags = (unsigned*)(ws + 2 * (size_t)kB * kR * 2);   // [4][32]

    hipMemsetAsync(flags, 0, 4 * kNB * sizeof(unsigned), stream);
    esn_persist<<<kBlocks, 512, 0, stream>>>(X, Win, W, out, s0, s1, flags);
}

// Round 9
// 3420.298 us; speedup vs baseline: 2.0559x; 1.5718x over previous
//
#include <hip/hip_runtime.h>
#include <hip/hip_fp16.h>
#include <cmath>

// Problem constants (reference: B=256, T=512, IN=64, R=2048)
constexpr int kB  = 256;
constexpr int kT  = 512;
constexpr int kIN = 64;
constexpr int kR  = 2048;

constexpr int kBands  = 8;             // m-bands; band = blockIdx&7 -> XCD-local under
                                       // round-robin dispatch (perf heuristic only)
constexpr int kNB     = 32;            // n-blocks per band
constexpr int kBlocks = kBands * kNB;  // 256 -> 1 block/CU
constexpr int BM = 32;                 // batches per block
constexpr int BN = 64;                 // n per block (W-band in registers, nh-split)
constexpr int CH  = 512;               // k per staged s-chunk (= 8 producer blocks)
constexpr int NCH = kR / CH;           // 4 chunks
constexpr int SST = CH + 8;            // ss row stride (halfs) = 520 -> <=2-way banks
constexpr int PFS = 68;                // partial-scratch row stride (words), <=2-way

typedef _Float16 f16x8 __attribute__((ext_vector_type(8)));
typedef float    f32x4 __attribute__((ext_vector_type(4)));
typedef unsigned long long u64;

#define MFMA16(a, b, c) __builtin_amdgcn_mfma_f32_16x16x32_f16((a), (b), (c), 0, 0, 0)

__device__ __forceinline__ f16x8 cvt8(float4 a, float4 b) {
    f16x8 v;
    v[0] = (_Float16)a.x; v[1] = (_Float16)a.y; v[2] = (_Float16)a.z; v[3] = (_Float16)a.w;
    v[4] = (_Float16)b.x; v[5] = (_Float16)b.y; v[6] = (_Float16)b.z; v[7] = (_Float16)b.w;
    return v;
}

// One coalesced poll of the band's 32 per-block flags (agent-scope, L3-fresh).
// Returns 32-bit mask: bit j set iff band-block j has published step >= target.
__device__ __forceinline__ unsigned poll32(const unsigned* f, int lane, unsigned target) {
    unsigned v = __hip_atomic_load(f + (lane & 31), __ATOMIC_RELAXED, __HIP_MEMORY_SCOPE_AGENT);
    return (unsigned)__ballot(v >= target);
}
// Chunk pc (512 k) is produced by band-blocks [8*pc, 8*pc+8).
__device__ __forceinline__ bool chunk_ready(unsigned fm, int pc) {
    return ((fm >> (8 * pc)) & 0xffu) == 0xffu;
}

// Persistent ESN, r9. Structure: 8 bands (BM=32, band = blockIdx&7, closed
// producer/consumer systems, XCD-co-located under round-robin dispatch) x 32
// n-blocks (BN=64). Waves = (n-half nh) x (k-phase q). K-loop: NCH=4 chunks of
// CH=512 with depth-2 register prefetch (loads for chunk c+2 issued during
// chunk c) over a double-buffered LDS stage — halves the serial L3 rounds of
// r8 and covers each with ~2 chunks of compute. One flag ballot per step
// (wave0, broadcast via LDS); in-loop re-polls only on a miss.
// Coherence (r5-proven, unchanged): agent-scope write-through s-stores ->
// s_waitcnt drain -> __syncthreads -> flag store; consumers: ONE acquire-inv
// per block per step, then plain cached coalesced loads.
__global__ __launch_bounds__(512, 2) void esn_persist(
    const float* __restrict__ X,     // [B, T, IN]
    const float* __restrict__ Win,   // [R, IN]
    const float* __restrict__ W,     // [R, R]
    float* __restrict__ out,         // [B, R]
    _Float16* __restrict__ sbuf0,
    _Float16* __restrict__ sbuf1,
    unsigned* __restrict__ flags)    // [8][32], zeroed at launch
{
    __shared__ __align__(16) _Float16 ss[2][BM * SST];   // 66560 B
    __shared__ __align__(16) float pf[4 * BM * PFS];     // 34816 B
    __shared__ unsigned fm_sh;

    const int tid  = threadIdx.x;
    const int wave = tid >> 6, lane = tid & 63;
    const int quad = lane >> 4, l16 = lane & 15;
    const int nh = wave >> 2;        // n-half: cols [nh*32, nh*32+32)
    const int q  = wave & 3;         // k-phase: kk ≡ q (mod 4)
    const int mb = blockIdx.x & 7;   // band (XCD-local heuristic)
    const int nb = blockIdx.x >> 3;  // n-block within band
    const int n0 = nb * BN;
    const int m0 = mb * BM;
    const int c0 = nb >> 3;          // own chunk / ring start (0..3)
    unsigned* bandflags = flags + mb * kNB;

    // ---- one-time: W-band -> register B-frags (f16), ring-permuted ----
    // Ring pos c -> physical chunk p(c) = (c0+c)&3.
    // wfrag[h][4c+j] = W[n0+nh*32+h*16+l16][kk*32+quad*8+..], kk = p(c)*16+4j+q
    f16x8 wfrag[2][4 * NCH];
    #pragma unroll
    for (int h = 0; h < 2; ++h) {
        const float* wrow = W + (size_t)(n0 + nh * 32 + h * 16 + l16) * kR;
        #pragma unroll
        for (int kki = 0; kki < 4 * NCH; ++kki) {
            const int kk = (((c0 + (kki >> 2)) & 3) << 4) + (kki & 3) * 4 + q;
            const float* p = wrow + kk * 32 + quad * 8;
            wfrag[h][kki] = cvt8(*(const float4*)p, *(const float4*)(p + 4));
        }
    }
    f16x8 winfrag[2] = {};
    if (q < 2) {
        #pragma unroll
        for (int h = 0; h < 2; ++h) {
            const float* p = Win + (size_t)(n0 + nh * 32 + h * 16 + l16) * kIN
                           + q * 32 + quad * 8;
            winfrag[h] = cvt8(*(const float4*)p, *(const float4*)(p + 4));
        }
    }

    // s staging geometry: thread -> row tid>>4 (0..31), 4 x 16B units at
    // (tid&15 + g*16)*16B within the 1024-B chunk row. Coalesced 256-B runs.
    const int srow = tid >> 4;
    const int su8  = (tid & 15) * 8;                 // halfs
    const size_t sgbase = (size_t)(m0 + srow) * kR + su8;
    const int ldst = srow * SST + su8;               // LDS halfs offset

    #pragma unroll 1
    for (int t = 0; t < kT; ++t) {
        // ---- X-frag raw loads for THIS step (latency hidden under sync) ----
        float4 xr[2][2];
        if (q < 2) {
            #pragma unroll
            for (int i = 0; i < 2; ++i) {
                const float* xp = X + ((size_t)(m0 + i * 16 + l16) * kT + t) * kIN
                                + q * 32 + quad * 8;
                xr[i][0] = *(const float4*)xp;
                xr[i][1] = *(const float4*)(xp + 4);
            }
        }

        f32x4 acc[2][2] = {};   // [m-tile][n-tile within n-half]

        // ---- recurrent term over s_{t-1}: 4 chunks, depth-2 prefetch ----
        if (t > 0) {
            const _Float16* sprev = (t & 1) ? sbuf0 : sbuf1;
            const unsigned target = (unsigned)t;   // flag >= t <=> s[t-1] published

            if (wave == 0) {
                unsigned fm = poll32(bandflags, lane, target);
                while (!chunk_ready(fm, c0)) {
                    __builtin_amdgcn_s_sleep(1);
                    fm = poll32(bandflags, lane, target);
                }
                // ONE inv per block per step: drop stale s lines from L1/L2
                __builtin_amdgcn_fence(__ATOMIC_ACQUIRE, "agent");
                if (lane == 0) fm_sh = fm;
            }
            __syncthreads();
            unsigned fmask = fm_sh;
            asm volatile("" ::: "memory");

            f16x8 rg[2][4];      // depth-2 register prefetch
            // chunk ring-0 (own, confirmed) loads
            #pragma unroll
            for (int g = 0; g < 4; ++g)
                rg[0][g] = *(const f16x8*)(sprev + sgbase + c0 * CH + g * 128);
            // chunk ring-1
            {
                const int pc1 = (c0 + 1) & 3;
                if (!chunk_ready(fmask, pc1)) {
                    do { __builtin_amdgcn_s_sleep(1);
                         fmask = poll32(bandflags, lane, target);
                    } while (!chunk_ready(fmask, pc1));
                }
                asm volatile("" ::: "memory");
                #pragma unroll
                for (int g = 0; g < 4; ++g)
                    rg[1][g] = *(const f16x8*)(sprev + sgbase + pc1 * CH + g * 128);
            }
            // stage ring-0 into buf0
            #pragma unroll
            for (int g = 0; g < 4; ++g)
                *(f16x8*)&ss[0][ldst + g * 128] = rg[0][g];
            __syncthreads();

            #pragma unroll
            for (int c = 0; c < NCH; ++c) {
                const _Float16* buf = ss[c & 1];
                #pragma unroll
                for (int j = 0; j < 4; ++j) {
                    const int kloc = (4 * j + q) * 32 + quad * 8;
                    f16x8 av0 = *(const f16x8*)&buf[(l16) * SST + kloc];
                    f16x8 av1 = *(const f16x8*)&buf[(16 + l16) * SST + kloc];
                    acc[0][0] = MFMA16(av0, wfrag[0][4 * c + j], acc[0][0]);
                    acc[0][1] = MFMA16(av0, wfrag[1][4 * c + j], acc[0][1]);
                    acc[1][0] = MFMA16(av1, wfrag[0][4 * c + j], acc[1][0]);
                    acc[1][1] = MFMA16(av1, wfrag[1][4 * c + j], acc[1][1]);
                }
                if (c + 2 < NCH) {   // issue loads 2 chunks ahead
                    const int pc = (c0 + c + 2) & 3;
                    if (!chunk_ready(fmask, pc)) {
                        do { __builtin_amdgcn_s_sleep(1);
                             fmask = poll32(bandflags, lane, target);
                        } while (!chunk_ready(fmask, pc));
                    }
                    asm volatile("" ::: "memory");
                    #pragma unroll
                    for (int g = 0; g < 4; ++g)
                        rg[c & 1][g] = *(const f16x8*)(sprev + sgbase + pc * CH + g * 128);
                }
                if (c + 1 < NCH) {   // stage next chunk into the other buffer
                    #pragma unroll
                    for (int g = 0; g < 4; ++g)
                        *(f16x8*)&ss[(c + 1) & 1][ldst + g * 128] = rg[(c + 1) & 1][g];
                }
                __syncthreads();
            }
        }

        // ---- input term (X loads long done) ----
        if (q < 2) {
            #pragma unroll
            for (int i = 0; i < 2; ++i) {
                f16x8 a = cvt8(xr[i][0], xr[i][1]);
                acc[i][0] = MFMA16(a, winfrag[0], acc[i][0]);
                acc[i][1] = MFMA16(a, winfrag[1], acc[i][1]);
            }
        }

        // ---- reduce 4 k-phase partials through LDS, tanh, store ----
        #pragma unroll
        for (int i = 0; i < 2; ++i)
            #pragma unroll
            for (int h = 0; h < 2; ++h)
                #pragma unroll
                for (int r = 0; r < 4; ++r)
                    pf[q * BM * PFS + (i * 16 + quad * 4 + r) * PFS + nh * 32 + h * 16 + l16]
                        = acc[i][h][r];
        __syncthreads();

        // thread -> (m = tid>>4, 4 n at (tid&15)*4)
        const int ml = tid >> 4, nl4 = (tid & 15) * 4;
        f32x4 v0 = *(const f32x4*)&pf[0 * BM * PFS + ml * PFS + nl4];
        f32x4 v1 = *(const f32x4*)&pf[1 * BM * PFS + ml * PFS + nl4];
        f32x4 v2 = *(const f32x4*)&pf[2 * BM * PFS + ml * PFS + nl4];
        f32x4 v3 = *(const f32x4*)&pf[3 * BM * PFS + ml * PFS + nl4];
        float o0 = tanhf(v0[0] + v1[0] + v2[0] + v3[0]);
        float o1 = tanhf(v0[1] + v1[1] + v2[1] + v3[1]);
        float o2 = tanhf(v0[2] + v1[2] + v2[2] + v3[2]);
        float o3 = tanhf(v0[3] + v1[3] + v2[3] + v3[3]);

        if (t < kT - 1) {
            _Float16* sout = (t & 1) ? sbuf1 : sbuf0;
            union { u64 u; _Float16 h[4]; } pk;
            pk.h[0] = (_Float16)o0; pk.h[1] = (_Float16)o1;
            pk.h[2] = (_Float16)o2; pk.h[3] = (_Float16)o3;
            // single write-through store to the coherence point
            __hip_atomic_store((u64*)(sout + (size_t)(m0 + ml) * kR + n0 + nl4), pk.u,
                               __ATOMIC_RELAXED, __HIP_MEMORY_SCOPE_AGENT);
            __builtin_amdgcn_s_waitcnt(0);   // this thread's store completed
            __syncthreads();                 // whole block's stores completed; guards pf
            if (tid == 0)
                __hip_atomic_store(&bandflags[nb], (unsigned)(t + 1),
                                   __ATOMIC_RELAXED, __HIP_MEMORY_SCOPE_AGENT);
        } else {
            float4 o; o.x = o0; o.y = o1; o.z = o2; o.w = o3;
            *(float4*)(out + (size_t)(m0 + ml) * kR + n0 + nl4) = o;
        }
    }
}

extern "C" void kernel_launch(void* const* d_in, const int* in_sizes, int n_in,
                              void* d_out, int out_size, void* d_ws, size_t ws_size,
                              hipStream_t stream)
{
    const float* X   = (const float*)d_in[0];  // [B, T, IN]
    const float* Win = (const float*)d_in[1];  // [R, IN]
    const float* W   = (const float*)d_in[2];  // [R, R]
    float* out = (float*)d_out;                // [B, R]

    char* ws = (char*)d_ws;
    _Float16* s0 = (_Float16*)ws;                                  // 1 MB
    _Float16* s1 = (_Float16*)(ws + (size_t)kB * kR * 2);          // 1 MB
    unsigned* flags = (unsigned*)(ws + 2 * (size_t)kB * kR * 2);   // [8][32]

    hipMemsetAsync(flags, 0, kBands * kNB * sizeof(unsigned), stream);
    esn_persist<<<kBlocks, 512, 0, stream>>>(X, Win, W, out, s0, s1, flags);
}